// Round 6
// baseline (170.602 us; speedup 1.0000x reference)
//
#include <hip/hip_runtime.h>
#include <hip/hip_bf16.h>

#define UNITS 128
#define NHEADS 8
#define SEQ 4096
#define BATCH 2
#define KVB 32                 // keys per iteration (wave-private tile)
#define QUARTER 1024           // keys per wave (4-way kv split)
#define NBLK (QUARTER / KVB)   // 32 iterations
#define QSCALE 0.3606737602f   // d^-0.5 * log2(e): logits in log2 domain
#define MASKNEG -1e30f
#define MINIT   -1e4f

typedef __bf16 bf8v __attribute__((ext_vector_type(8)));
typedef float  f4v  __attribute__((ext_vector_type(4)));
typedef float  f16v __attribute__((ext_vector_type(16)));

union BF2  { __bf16 h[2]; unsigned int u; };
union FRAG { unsigned int u[4]; bf8v v; };
union C16  { f16v v; f4v q[4]; };

__device__ __forceinline__ float fmax3(float a, float b, float c) {
    return fmaxf(fmaxf(a, b), c);
}

// Per-wave LDS region (4224 B): K[32 keys][24 bf16] (48B pitch, 1536B),
// V^T[32 d][40 bf16] (80B pitch, 2560B; rows 16..31 const: row16=1, else 0),
// maskrep[32] f32 (128B, pre-permuted to C-operand order).
// No barriers in the main loop - tiles are wave-private (same-wave DS order).
#define WBYTES 4224
#define VOFF   1536
#define MOFF   4096

__global__ __launch_bounds__(256, 6) void attn_fwd(
    const float* __restrict__ memory, const float* __restrict__ query,
    const int* __restrict__ seq_mask, float* __restrict__ out)
{
    const int bidx = blockIdx.z, hh = blockIdx.y, qblk = blockIdx.x;
    const int tid  = threadIdx.x;
    const int wave = tid >> 6;          // = kv quarter
    const int lane = tid & 63, col = lane & 31, hl = lane >> 5;

    __shared__ __align__(16) char smem[4 * WBYTES];   // 16896 B
    char* wb = smem + wave * WBYTES;
    char* Kb = wb;
    char* Vb = wb + VOFF;
    char* Mb = wb + MOFF;

    // ---- V^T const rows 16..31: row16 = 1.0 (free denominator), others 0
    #pragma unroll
    for (int idx = lane; idx < 256; idx += 64) {
        const int d = 16 + (idx >> 4), kp2 = (idx & 15) * 2;
        *(unsigned int*)(Vb + d * 80 + kp2 * 2) = (d == 16) ? 0x3F803F80u : 0u;
    }

    // ---- Q fragment (B operand): k = d = hl*8+j (K=16 = d_head exactly)
    const int qrow = qblk * 32 + col;
    bf8v qfrag;
    {
        const float* qp = query + ((size_t)bidx * SEQ + qrow) * UNITS + hh * 16 + hl * 8;
        #pragma unroll
        for (int j = 0; j < 8; ++j) qfrag[j] = (__bf16)(qp[j] * QSCALE);
    }

    // ---- staging assignments (wave-private, 64 lanes stage 32 keys)
    const int kq = lane >> 1, part = lane & 1;             // K: key kq, d part*8..+7
    const int kva = (lane & 15) * 2, dv = (lane >> 4) * 4; // V: keys kva,kva+1, d dv..dv+3
    const int mkey = 8 * ((lane >> 2) & 3) + 4 * (lane >> 4) + (lane & 3); // lane<32: C-order permute

    const size_t membase = (size_t)bidx * SEQ * (2 * UNITS);
    const int kv0 = wave * QUARTER;
    const float* kp = memory + membase + (size_t)(kv0 + kq) * (2 * UNITS) + hh * 16 + part * 8;
    const float* vp = memory + membase + (size_t)(kv0 + kva) * (2 * UNITS) + UNITS + hh * 16 + dv;
    const int*   mp = seq_mask + (size_t)bidx * SEQ + kv0 + mkey;

    // prologue loads (iter 0)
    f4v ka  = *(const f4v*)kp;
    f4v kb2 = *(const f4v*)(kp + 4);
    f4v va  = *(const f4v*)vp;
    f4v vb2 = *(const f4v*)(vp + 2 * UNITS);
    int mreg = (lane < 32) ? *mp : 0;

    float m = MINIT;
    f16v acc;
    #pragma unroll
    for (int i = 0; i < 16; ++i) acc[i] = 0.f;

    for (int blk = 0; blk < NBLK; ++blk) {
        // ---- staged regs -> wave-private LDS (no barrier)
        {
            bf8v k8;
            #pragma unroll
            for (int i = 0; i < 4; ++i) { k8[i] = (__bf16)ka[i]; k8[4 + i] = (__bf16)kb2[i]; }
            *(bf8v*)(Kb + kq * 48 + part * 16) = k8;
            #pragma unroll
            for (int i = 0; i < 4; ++i) {
                BF2 p; p.h[0] = (__bf16)va[i]; p.h[1] = (__bf16)vb2[i];
                *(unsigned int*)(Vb + (dv + i) * 80 + kva * 2) = p.u;
            }
            if (lane < 32) *(float*)(Mb + lane * 4) = mreg ? 0.f : MASKNEG;
        }

        // ---- prefetch next iteration's globals (land under this iter's compute)
        if (blk + 1 < NBLK) {
            kp += KVB * 2 * UNITS;
            vp += KVB * 2 * UNITS;
            mp += KVB;
            ka  = *(const f4v*)kp;
            kb2 = *(const f4v*)(kp + 4);
            va  = *(const f4v*)vp;
            vb2 = *(const f4v*)(vp + 2 * UNITS);
            if (lane < 32) mreg = *mp;
        }

        // ---- QK^T (swapped): D[key][q], mask rides the C operand
        bf8v kfrag = *(bf8v*)(Kb + col * 48 + hl * 16);
        C16 cma;
        #pragma unroll
        for (int i = 0; i < 4; ++i) cma.q[i] = *(const f4v*)(Mb + hl * 64 + i * 16);
        f16v sv = __builtin_amdgcn_mfma_f32_32x32x16_bf16(kfrag, qfrag, cma.v, 0, 0, 0);

        // ---- block max: max3 tree + 1 shfl (keys for q=col split across hl pair)
        float p0 = fmax3(sv[0], sv[1], sv[2]);
        float p1 = fmax3(sv[3], sv[4], sv[5]);
        float p2 = fmax3(sv[6], sv[7], sv[8]);
        float p3 = fmax3(sv[9], sv[10], sv[11]);
        float p4 = fmax3(sv[12], sv[13], sv[14]);
        float bmax = fmaxf(fmax3(p0, p1, p2), fmax3(p3, p4, sv[15]));
        bmax = fmaxf(bmax, __shfl_xor(bmax, 32));

        // ---- T13 defer-max (log2 domain): acc[8] is the running denominator (hl=0)
        if (!__all(bmax <= m + 11.0f)) {
            const float m_new = fmaxf(m, bmax);
            const float sc = exp2f(m - m_new);
            #pragma unroll
            for (int r = 0; r < 9; ++r) acc[r] *= sc;
            m = m_new;
        }

        // ---- exp2 + pack to bf16 dwords: pk[R] = keys {8R+4hl+0..3} for q=col
        unsigned int pk[4][2];
        #pragma unroll
        for (int R = 0; R < 4; ++R) {
            #pragma unroll
            for (int p = 0; p < 2; ++p) {
                BF2 a;
                a.h[0] = (__bf16)exp2f(sv[4 * R + 2 * p]     - m);
                a.h[1] = (__bf16)exp2f(sv[4 * R + 2 * p + 1] - m);
                pk[R][p] = a.u;
            }
        }

        // ---- PV: B-frag via shfl_xor(32) exchange (round-4-verified pattern)
        // chunk ck needs keys 16ck+8hl+j (q=col); lo 4 keys from hl=0's pk[2ck+hl],
        // hi 4 keys from hl=1's pk[2ck+hl]
        #pragma unroll
        for (int ck = 0; ck < 2; ++ck) {
            unsigned int own0 = hl ? pk[2 * ck + 1][0] : pk[2 * ck][0];
            unsigned int own1 = hl ? pk[2 * ck + 1][1] : pk[2 * ck][1];
            unsigned int snd0 = hl ? pk[2 * ck][0]     : pk[2 * ck + 1][0];
            unsigned int snd1 = hl ? pk[2 * ck][1]     : pk[2 * ck + 1][1];
            const unsigned int x0 = (unsigned int)__shfl_xor((int)snd0, 32);
            const unsigned int x1 = (unsigned int)__shfl_xor((int)snd1, 32);
            FRAG pf;
            pf.u[0] = hl ? x0 : own0;
            pf.u[1] = hl ? x1 : own1;
            pf.u[2] = hl ? own0 : x0;
            pf.u[3] = hl ? own1 : x1;
            bf8v vfrag = *(bf8v*)(Vb + col * 80 + ck * 32 + hl * 16);
            acc = __builtin_amdgcn_mfma_f32_32x32x16_bf16(vfrag, pf.v, acc, 0, 0, 0);
        }
    }

    // ---- denominator share across hl (row16 sum lives in hl=0's acc[8]; hl=1's is 0)
    const float l = acc[8] + __shfl_xor(acc[8], 32);

    // ---- merge the 4 kv-quarters: waves 1-3 publish, wave 0 combines
    __syncthreads();
    float* mrg = (float*)smem;           // [3][32][20] f32 (reuses staging LDS)
    if (wave != 0) {
        float* row = mrg + ((wave - 1) * 32 + col) * 20;
        f4v a0, a1;
        #pragma unroll
        for (int i = 0; i < 4; ++i) { a0[i] = acc[i]; a1[i] = acc[4 + i]; }
        *(f4v*)(row + 4 * hl)     = a0;   // d rows 4hl..4hl+3
        *(f4v*)(row + 8 + 4 * hl) = a1;   // d rows 8+4hl..11+4hl
        if (hl == 0) { row[16] = m; row[17] = l; }
    }
    __syncthreads();
    if (wave == 0) {
        float mw[3], lw[3];
        f4v a0w[3], a1w[3];
        #pragma unroll
        for (int w = 0; w < 3; ++w) {
            const float* row = mrg + (w * 32 + col) * 20;
            a0w[w] = *(const f4v*)(row + 4 * hl);
            a1w[w] = *(const f4v*)(row + 8 + 4 * hl);
            mw[w] = row[16];
            lw[w] = row[17];
        }
        float M = fmaxf(fmaxf(m, mw[0]), fmaxf(mw[1], mw[2]));
        const float w0 = exp2f(m - M);
        float ww[3];
        #pragma unroll
        for (int w = 0; w < 3; ++w) ww[w] = exp2f(mw[w] - M);
        const float denom = l * w0 + lw[0] * ww[0] + lw[1] * ww[1] + lw[2] * ww[2];
        const float inv = 1.0f / denom;
        f4v o0, o1;
        #pragma unroll
        for (int i = 0; i < 4; ++i) {
            o0[i] = (acc[i]     * w0 + a0w[0][i] * ww[0] + a0w[1][i] * ww[1] + a0w[2][i] * ww[2]) * inv;
            o1[i] = (acc[4 + i] * w0 + a1w[0][i] * ww[0] + a1w[1][i] * ww[1] + a1w[2][i] * ww[2]) * inv;
        }
        float* op = out + ((size_t)bidx * SEQ + qrow) * UNITS + hh * 16;
        *(f4v*)(op + 4 * hl)     = o0;
        *(f4v*)(op + 8 + 4 * hl) = o1;
    }
}

extern "C" void kernel_launch(void* const* d_in, const int* in_sizes, int n_in,
                              void* d_out, int out_size, void* d_ws, size_t ws_size,
                              hipStream_t stream) {
    const float* memory   = (const float*)d_in[0];
    const float* query    = (const float*)d_in[1];
    const int*   seq_mask = (const int*)d_in[2];
    float*       out      = (float*)d_out;
    dim3 grid(SEQ / 32, NHEADS, BATCH);
    attn_fwd<<<grid, 256, 0, stream>>>(memory, query, seq_mask, out);
}

// Round 7
// 137.532 us; speedup vs baseline: 1.2405x; 1.2405x over previous
//
#include <hip/hip_runtime.h>
#include <hip/hip_bf16.h>

#define UNITS 128
#define NHEADS 8
#define SEQ 4096
#define BATCH 2
#define KVB 32                 // keys per iteration (wave-private tile)
#define QUARTER 1024           // keys per wave (4-way kv split)
#define NBLK (QUARTER / KVB)   // 32 iterations
#define QSCALE 0.3606737602f   // d^-0.5 * log2(e): logits in log2 domain
#define MASKNEG -1e30f
#define MINIT   -1e4f

typedef __bf16 bf8v __attribute__((ext_vector_type(8)));
typedef float  f4v  __attribute__((ext_vector_type(4)));
typedef float  f16v __attribute__((ext_vector_type(16)));

union BF2  { __bf16 h[2]; unsigned int u; };
union FRAG { unsigned int u[4]; bf8v v; };
union C16  { f16v v; f4v q[4]; };

__device__ __forceinline__ float fmax3(float a, float b, float c) {
    return fmaxf(fmaxf(a, b), c);
}

// Per-wave LDS region (4224 B): K[32 keys][24 bf16] (48B pitch, 1536B),
// V^T[32 d][40 bf16] (80B pitch, 2560B; rows 16..31 const: row16=1, else 0),
// maskrep[32] f32 (128B, pre-permuted to C-operand order).
// No barriers in the main loop - tiles are wave-private (same-wave DS order).
#define WBYTES 4224
#define VOFF   1536
#define MOFF   4096

// (256,4): VGPR cap 128. (256,6) capped at 80 and spilled 300MB of scratch (R6);
// (512,8) capped at 64 and spilled (R3). Do not raise the min-waves arg again.
__global__ __launch_bounds__(256, 4) void attn_fwd(
    const float* __restrict__ memory, const float* __restrict__ query,
    const int* __restrict__ seq_mask, float* __restrict__ out)
{
    const int bidx = blockIdx.z, hh = blockIdx.y, qblk = blockIdx.x;
    const int tid  = threadIdx.x;
    const int wave = tid >> 6;          // = kv quarter
    const int lane = tid & 63, col = lane & 31, hl = lane >> 5;

    __shared__ __align__(16) char smem[4 * WBYTES];   // 16896 B
    char* wb = smem + wave * WBYTES;
    char* Kb = wb;
    char* Vb = wb + VOFF;
    char* Mb = wb + MOFF;

    // ---- V^T const rows 16..31: row16 = 1.0 (free denominator), others 0
    #pragma unroll
    for (int idx = lane; idx < 256; idx += 64) {
        const int d = 16 + (idx >> 4), kp2 = (idx & 15) * 2;
        *(unsigned int*)(Vb + d * 80 + kp2 * 2) = (d == 16) ? 0x3F803F80u : 0u;
    }

    // ---- Q fragment (B operand): k = d = hl*8+j (K=16 = d_head exactly)
    const int qrow = qblk * 32 + col;
    bf8v qfrag;
    {
        const float* qp = query + ((size_t)bidx * SEQ + qrow) * UNITS + hh * 16 + hl * 8;
        #pragma unroll
        for (int j = 0; j < 8; ++j) qfrag[j] = (__bf16)(qp[j] * QSCALE);
    }

    // ---- staging assignments (wave-private, 64 lanes stage 32 keys)
    const int kq = lane >> 1, part = lane & 1;             // K: key kq, d part*8..+7
    const int kva = (lane & 15) * 2, dv = (lane >> 4) * 4; // V: keys kva,kva+1, d dv..dv+3
    const int mkey = 8 * ((lane >> 2) & 3) + 4 * (lane >> 4) + (lane & 3); // lane<32: C-order permute

    const size_t membase = (size_t)bidx * SEQ * (2 * UNITS);
    const int kv0 = wave * QUARTER;
    const float* kp = memory + membase + (size_t)(kv0 + kq) * (2 * UNITS) + hh * 16 + part * 8;
    const float* vp = memory + membase + (size_t)(kv0 + kva) * (2 * UNITS) + UNITS + hh * 16 + dv;
    const int*   mp = seq_mask + (size_t)bidx * SEQ + kv0 + mkey;

    // prologue loads (iter 0)
    f4v ka  = *(const f4v*)kp;
    f4v kb2 = *(const f4v*)(kp + 4);
    f4v va  = *(const f4v*)vp;
    f4v vb2 = *(const f4v*)(vp + 2 * UNITS);
    int mreg = (lane < 32) ? *mp : 0;

    float m = MINIT;
    f16v acc;
    #pragma unroll
    for (int i = 0; i < 16; ++i) acc[i] = 0.f;

    for (int blk = 0; blk < NBLK; ++blk) {
        // ---- staged regs -> wave-private LDS (no barrier)
        {
            bf8v k8;
            #pragma unroll
            for (int i = 0; i < 4; ++i) { k8[i] = (__bf16)ka[i]; k8[4 + i] = (__bf16)kb2[i]; }
            *(bf8v*)(Kb + kq * 48 + part * 16) = k8;
            #pragma unroll
            for (int i = 0; i < 4; ++i) {
                BF2 p; p.h[0] = (__bf16)va[i]; p.h[1] = (__bf16)vb2[i];
                *(unsigned int*)(Vb + (dv + i) * 80 + kva * 2) = p.u;
            }
            if (lane < 32) *(float*)(Mb + lane * 4) = mreg ? 0.f : MASKNEG;
        }

        // ---- prefetch next iteration's globals (land under this iter's compute)
        if (blk + 1 < NBLK) {
            kp += KVB * 2 * UNITS;
            vp += KVB * 2 * UNITS;
            mp += KVB;
            ka  = *(const f4v*)kp;
            kb2 = *(const f4v*)(kp + 4);
            va  = *(const f4v*)vp;
            vb2 = *(const f4v*)(vp + 2 * UNITS);
            if (lane < 32) mreg = *mp;
        }

        // ---- QK^T (swapped): D[key][q], mask rides the C operand
        bf8v kfrag = *(bf8v*)(Kb + col * 48 + hl * 16);
        C16 cma;
        #pragma unroll
        for (int i = 0; i < 4; ++i) cma.q[i] = *(const f4v*)(Mb + hl * 64 + i * 16);
        f16v sv = __builtin_amdgcn_mfma_f32_32x32x16_bf16(kfrag, qfrag, cma.v, 0, 0, 0);

        // ---- block max: max3 tree + 1 shfl (keys for q=col split across hl pair)
        float p0 = fmax3(sv[0], sv[1], sv[2]);
        float p1 = fmax3(sv[3], sv[4], sv[5]);
        float p2 = fmax3(sv[6], sv[7], sv[8]);
        float p3 = fmax3(sv[9], sv[10], sv[11]);
        float p4 = fmax3(sv[12], sv[13], sv[14]);
        float bmax = fmaxf(fmax3(p0, p1, p2), fmax3(p3, p4, sv[15]));
        bmax = fmaxf(bmax, __shfl_xor(bmax, 32));

        // ---- T13 defer-max (log2 domain): acc[8] is the running denominator (hl=0)
        if (!__all(bmax <= m + 11.0f)) {
            const float m_new = fmaxf(m, bmax);
            const float sc = exp2f(m - m_new);
            #pragma unroll
            for (int r = 0; r < 9; ++r) acc[r] *= sc;
            m = m_new;
        }

        // ---- exp2 + pack to bf16 dwords: pk[R] = keys {8R+4hl+0..3} for q=col
        unsigned int pk[4][2];
        #pragma unroll
        for (int R = 0; R < 4; ++R) {
            #pragma unroll
            for (int p = 0; p < 2; ++p) {
                BF2 a;
                a.h[0] = (__bf16)exp2f(sv[4 * R + 2 * p]     - m);
                a.h[1] = (__bf16)exp2f(sv[4 * R + 2 * p + 1] - m);
                pk[R][p] = a.u;
            }
        }

        // ---- PV: B-frag via shfl_xor(32) exchange (round-4-verified pattern)
        #pragma unroll
        for (int ck = 0; ck < 2; ++ck) {
            unsigned int own0 = hl ? pk[2 * ck + 1][0] : pk[2 * ck][0];
            unsigned int own1 = hl ? pk[2 * ck + 1][1] : pk[2 * ck][1];
            unsigned int snd0 = hl ? pk[2 * ck][0]     : pk[2 * ck + 1][0];
            unsigned int snd1 = hl ? pk[2 * ck][1]     : pk[2 * ck + 1][1];
            const unsigned int x0 = (unsigned int)__shfl_xor((int)snd0, 32);
            const unsigned int x1 = (unsigned int)__shfl_xor((int)snd1, 32);
            FRAG pf;
            pf.u[0] = hl ? x0 : own0;
            pf.u[1] = hl ? x1 : own1;
            pf.u[2] = hl ? own0 : x0;
            pf.u[3] = hl ? own1 : x1;
            bf8v vfrag = *(bf8v*)(Vb + col * 80 + ck * 32 + hl * 16);
            acc = __builtin_amdgcn_mfma_f32_32x32x16_bf16(vfrag, pf.v, acc, 0, 0, 0);
        }
    }

    // ---- denominator share across hl (row16 sum lives in hl=0's acc[8]; hl=1's is 0)
    const float l = acc[8] + __shfl_xor(acc[8], 32);

    // ---- merge the 4 kv-quarters: waves 1-3 publish, wave 0 combines
    __syncthreads();
    float* mrg = (float*)smem;           // [3][32][20] f32 (reuses staging LDS)
    if (wave != 0) {
        float* row = mrg + ((wave - 1) * 32 + col) * 20;
        f4v a0, a1;
        #pragma unroll
        for (int i = 0; i < 4; ++i) { a0[i] = acc[i]; a1[i] = acc[4 + i]; }
        *(f4v*)(row + 4 * hl)     = a0;   // d rows 4hl..4hl+3
        *(f4v*)(row + 8 + 4 * hl) = a1;   // d rows 8+4hl..11+4hl
        if (hl == 0) { row[16] = m; row[17] = l; }
    }
    __syncthreads();
    if (wave == 0) {
        float mw[3], lw[3];
        f4v a0w[3], a1w[3];
        #pragma unroll
        for (int w = 0; w < 3; ++w) {
            const float* row = mrg + (w * 32 + col) * 20;
            a0w[w] = *(const f4v*)(row + 4 * hl);
            a1w[w] = *(const f4v*)(row + 8 + 4 * hl);
            mw[w] = row[16];
            lw[w] = row[17];
        }
        float M = fmaxf(fmaxf(m, mw[0]), fmaxf(mw[1], mw[2]));
        const float w0 = exp2f(m - M);
        float ww[3];
        #pragma unroll
        for (int w = 0; w < 3; ++w) ww[w] = exp2f(mw[w] - M);
        const float denom = l * w0 + lw[0] * ww[0] + lw[1] * ww[1] + lw[2] * ww[2];
        const float inv = 1.0f / denom;
        f4v o0, o1;
        #pragma unroll
        for (int i = 0; i < 4; ++i) {
            o0[i] = (acc[i]     * w0 + a0w[0][i] * ww[0] + a0w[1][i] * ww[1] + a0w[2][i] * ww[2]) * inv;
            o1[i] = (acc[4 + i] * w0 + a1w[0][i] * ww[0] + a1w[1][i] * ww[1] + a1w[2][i] * ww[2]) * inv;
        }
        float* op = out + ((size_t)bidx * SEQ + qrow) * UNITS + hh * 16;
        *(f4v*)(op + 4 * hl)     = o0;
        *(f4v*)(op + 8 + 4 * hl) = o1;
    }
}

extern "C" void kernel_launch(void* const* d_in, const int* in_sizes, int n_in,
                              void* d_out, int out_size, void* d_ws, size_t ws_size,
                              hipStream_t stream) {
    const float* memory   = (const float*)d_in[0];
    const float* query    = (const float*)d_in[1];
    const int*   seq_mask = (const int*)d_in[2];
    float*       out      = (float*)d_out;
    dim3 grid(SEQ / 32, NHEADS, BATCH);
    attn_fwd<<<grid, 256, 0, stream>>>(memory, query, seq_mask, out);
}

// Round 8
// 132.619 us; speedup vs baseline: 1.2864x; 1.0370x over previous
//
#include <hip/hip_runtime.h>
#include <hip/hip_bf16.h>

#define UNITS 128
#define NHEADS 8
#define SEQ 4096
#define BATCH 2
#define QSCALE 0.3606737602f   // d^-0.5 * log2(e): logits in log2 domain
#define MASKNEG -1e30f
#define MINIT   -1e4f

typedef __bf16 bf8v __attribute__((ext_vector_type(8)));
typedef float  f4v  __attribute__((ext_vector_type(4)));
typedef float  f16v __attribute__((ext_vector_type(16)));

union BF2  { __bf16 h[2]; unsigned int u; };
union FRAG { unsigned int u[4]; bf8v v; };
union C16  { f16v v; f4v q[4]; };
union BF8U { __bf16 h[8]; bf8v v; };

// workspace layout (bytes)
#define KP_OFF 0u            // K' [B][H][S][16] bf16   : 2 MB
#define QP_OFF (2u << 20)    // Q' [B][H][S][16] bf16   : 2 MB (pre-scaled)
#define VP_OFF (4u << 20)    // V' [B][H][S/32][32][32] : 4 MB (rows 16-31 = 1.0)
#define MC_OFF (8u << 20)    // maskC [B][128][2][16] f32 : 32 KB (C-operand order)

__device__ __forceinline__ float fmax3(float a, float b, float c) {
    return fmaxf(fmaxf(a, b), c);
}

// ---------------- prep 1: K', Q' (bf16, head-separated), maskC (C-order) ----
__global__ void prep_kqm(const float* __restrict__ mem, const float* __restrict__ qry,
                         const int* __restrict__ msk, char* __restrict__ ws)
{
    const int gid = blockIdx.x * 256 + threadIdx.x;   // 8192 = B*S
    const int b = gid >> 12, key = gid & 4095;

    // mask -> C-operand permuted order: C row = (r&3) + 8*(r>>2) + 4*hl
    const float mv = msk[b * SEQ + key] ? 0.f : MASKNEG;
    const int pos = key & 31, blkg = key >> 5;
    const int hl = (pos >> 2) & 1;
    const int r  = (pos & 3) | ((pos >> 3) << 2);
    ((float*)(ws + MC_OFF))[((b * 128 + blkg) * 2 + hl) * 16 + r] = mv;

    const float* krow = mem + ((size_t)(b * SEQ + key)) * (2 * UNITS);
    const float* qrow = qry + ((size_t)(b * SEQ + key)) * UNITS;
    #pragma unroll
    for (int h = 0; h < NHEADS; ++h) {
        BF8U lo, hi;
        #pragma unroll
        for (int j = 0; j < 8; ++j) {
            lo.h[j] = (__bf16)krow[h * 16 + j];
            hi.h[j] = (__bf16)krow[h * 16 + 8 + j];
        }
        __bf16* kd = (__bf16*)(ws + KP_OFF) + ((size_t)(b * 8 + h) * SEQ + key) * 16;
        *(bf8v*)kd = lo.v;
        *(bf8v*)(kd + 8) = hi.v;
        #pragma unroll
        for (int j = 0; j < 8; ++j) {
            lo.h[j] = (__bf16)(qrow[h * 16 + j] * QSCALE);
            hi.h[j] = (__bf16)(qrow[h * 16 + 8 + j] * QSCALE);
        }
        __bf16* qd = (__bf16*)(ws + QP_OFF) + ((size_t)(b * 8 + h) * SEQ + key) * 16;
        *(bf8v*)qd = lo.v;
        *(bf8v*)(qd + 8) = hi.v;
    }
}

// ---------------- prep 2: V' transposed per 32-key block, ones rows baked ----
__global__ void prep_v(const float* __restrict__ mem, char* __restrict__ ws)
{
    const int wg = blockIdx.x;                 // B*H*128
    const int b = wg >> 10, rem = wg & 1023;
    const int h = rem >> 7, blk = rem & 127;
    const int t = threadIdx.x;                 // 128

    __shared__ float vt[32][17];
    {
        const int key = t >> 2, q4 = t & 3;
        const float* src = mem + ((size_t)(b * SEQ + blk * 32 + key)) * (2 * UNITS)
                           + UNITS + h * 16 + q4 * 4;
        const f4v v = *(const f4v*)src;
        vt[key][q4 * 4 + 0] = v[0]; vt[key][q4 * 4 + 1] = v[1];
        vt[key][q4 * 4 + 2] = v[2]; vt[key][q4 * 4 + 3] = v[3];
    }
    __syncthreads();
    const int row = t >> 2, c = t & 3;         // row = d-slot 0..31, c = key-octet
    BF8U o;
    #pragma unroll
    for (int k = 0; k < 8; ++k)
        o.h[k] = (row < 16) ? (__bf16)vt[c * 8 + k][row] : (__bf16)1.0f;
    __bf16* dst = (__bf16*)(ws + VP_OFF)
                  + (((size_t)(b * 8 + h) * 128 + blk) * 32 + row) * 32 + c * 8;
    *(bf8v*)dst = o.v;
}

// ---------------- attention: zero-LDS main loop, wave-private kv quarters ----
__global__ __launch_bounds__(256, 4) void attn_fwd(
    const char* __restrict__ ws, float* __restrict__ out)
{
    const int qblk = blockIdx.x, h = blockIdx.y, b = blockIdx.z;
    const int tid  = threadIdx.x;
    const int wave = tid >> 6;                 // kv quarter
    const int lane = tid & 63, col = lane & 31, hl = lane >> 5;

    __shared__ float mrg[3][32][20];

    const size_t bh = (size_t)(b * 8 + h);
    const char* Kb = ws + KP_OFF + bh * SEQ * 32;
    const char* Qb = ws + QP_OFF + bh * SEQ * 32;
    const char* Vb = ws + VP_OFF + bh * 128 * 2048;
    const char* Mb = ws + MC_OFF + (size_t)b * 128 * 128;

    // Q fragment: B[k=d=hl*8+j][col=q]
    const int qrow = qblk * 32 + col;
    const bf8v qfrag = *(const bf8v*)(Qb + (size_t)qrow * 32 + hl * 16);

    // per-lane frag addresses (advance by constants each iter)
    const char* kaddr = Kb + (size_t)(wave * 1024 + col) * 32 + hl * 16;
    const char* vaddr = Vb + (size_t)(wave * 32) * 2048 + col * 64 + hl * 16;
    const char* maddr = Mb + (size_t)(wave * 32) * 128 + hl * 64;

    // prologue: iter-0 fragments
    bf8v kf = *(const bf8v*)kaddr;
    bf8v v0 = *(const bf8v*)vaddr;
    bf8v v1 = *(const bf8v*)(vaddr + 32);

    float m = MINIT;
    f16v acc;
    #pragma unroll
    for (int i = 0; i < 16; ++i) acc[i] = 0.f;

    for (int blk = 0; blk < 32; ++blk) {
        // mask C operand (pre-permuted, L1-hot broadcast)
        C16 cma;
        #pragma unroll
        for (int i = 0; i < 4; ++i) cma.q[i] = *(const f4v*)(maddr + i * 16);

        // QK^T (swapped): D[key][q] = K.Q + maskC
        const f16v sv = __builtin_amdgcn_mfma_f32_32x32x16_bf16(kf, qfrag, cma.v, 0, 0, 0);

        // prefetch next iteration's fragments (pure register loads, no barrier)
        if (blk + 1 < 32) {
            kaddr += 1024; vaddr += 2048; maddr += 128;
            kf = *(const bf8v*)kaddr;
            v0p_label:;
        }
        bf8v v0n = v0, v1n = v1;
        if (blk + 1 < 32) {
            v0n = *(const bf8v*)vaddr;
            v1n = *(const bf8v*)(vaddr + 32);
        }

        // block max: max3 tree + 1 shfl
        float p0 = fmax3(sv[0], sv[1], sv[2]);
        float p1 = fmax3(sv[3], sv[4], sv[5]);
        float p2 = fmax3(sv[6], sv[7], sv[8]);
        float p3 = fmax3(sv[9], sv[10], sv[11]);
        float p4 = fmax3(sv[12], sv[13], sv[14]);
        float bmax = fmaxf(fmax3(p0, p1, p2), fmax3(p3, p4, sv[15]));
        bmax = fmaxf(bmax, __shfl_xor(bmax, 32));

        // T13 defer-max (log2 domain); acc[8] = running denominator (all lanes)
        if (!__all(bmax <= m + 11.0f)) {
            const float m_new = fmaxf(m, bmax);
            const float sc = exp2f(m - m_new);
            #pragma unroll
            for (int r2 = 0; r2 < 9; ++r2) acc[r2] *= sc;
            m = m_new;
        }

        // exp2 + pack: pk[R][p] = keys {8R+4hl+2p, +1} for q=col
        unsigned int pk[4][2];
        #pragma unroll
        for (int R = 0; R < 4; ++R) {
            #pragma unroll
            for (int p = 0; p < 2; ++p) {
                BF2 a;
                a.h[0] = (__bf16)exp2f(sv[4 * R + 2 * p]     - m);
                a.h[1] = (__bf16)exp2f(sv[4 * R + 2 * p + 1] - m);
                pk[R][p] = a.u;
            }
        }

        // PV: B-frag via shfl_xor(32) exchange (R7-verified pattern)
        #pragma unroll
        for (int ck = 0; ck < 2; ++ck) {
            unsigned int own0 = hl ? pk[2 * ck + 1][0] : pk[2 * ck][0];
            unsigned int own1 = hl ? pk[2 * ck + 1][1] : pk[2 * ck][1];
            unsigned int snd0 = hl ? pk[2 * ck][0]     : pk[2 * ck + 1][0];
            unsigned int snd1 = hl ? pk[2 * ck][1]     : pk[2 * ck + 1][1];
            const unsigned int x0 = (unsigned int)__shfl_xor((int)snd0, 32);
            const unsigned int x1 = (unsigned int)__shfl_xor((int)snd1, 32);
            FRAG pf;
            pf.u[0] = hl ? x0 : own0;
            pf.u[1] = hl ? x1 : own1;
            pf.u[2] = hl ? own0 : x0;
            pf.u[3] = hl ? own1 : x1;
            acc = __builtin_amdgcn_mfma_f32_32x32x16_bf16(ck ? v1 : v0, pf.v, acc, 0, 0, 0);
        }
        v0 = v0n; v1 = v1n;
    }

    // denominator: V' rows 16-31 = 1.0 -> acc[8] holds sum(P) in every lane
    const float l = acc[8];

    // merge the 4 kv quarters (R7-verified epilogue)
    __syncthreads();
    if (wave != 0) {
        float* row = &mrg[wave - 1][col][0];
        f4v a0, a1;
        #pragma unroll
        for (int i = 0; i < 4; ++i) { a0[i] = acc[i]; a1[i] = acc[4 + i]; }
        *(f4v*)(row + 4 * hl)     = a0;
        *(f4v*)(row + 8 + 4 * hl) = a1;
        if (hl == 0) { row[16] = m; row[17] = l; }
    }
    __syncthreads();
    if (wave == 0) {
        float mw[3], lw[3];
        f4v a0w[3], a1w[3];
        #pragma unroll
        for (int w = 0; w < 3; ++w) {
            const float* row = &mrg[w][col][0];
            a0w[w] = *(const f4v*)(row + 4 * hl);
            a1w[w] = *(const f4v*)(row + 8 + 4 * hl);
            mw[w] = row[16];
            lw[w] = row[17];
        }
        const float M = fmaxf(fmaxf(m, mw[0]), fmaxf(mw[1], mw[2]));
        const float w0 = exp2f(m - M);
        float ww[3];
        #pragma unroll
        for (int w = 0; w < 3; ++w) ww[w] = exp2f(mw[w] - M);
        const float inv = 1.0f / (l * w0 + lw[0] * ww[0] + lw[1] * ww[1] + lw[2] * ww[2]);
        f4v o0, o1;
        #pragma unroll
        for (int i = 0; i < 4; ++i) {
            o0[i] = (acc[i]     * w0 + a0w[0][i] * ww[0] + a0w[1][i] * ww[1] + a0w[2][i] * ww[2]) * inv;
            o1[i] = (acc[4 + i] * w0 + a1w[0][i] * ww[0] + a1w[1][i] * ww[1] + a1w[2][i] * ww[2]) * inv;
        }
        float* op = out + ((size_t)b * SEQ + qrow) * UNITS + h * 16;
        *(f4v*)(op + 4 * hl)     = o0;
        *(f4v*)(op + 8 + 4 * hl) = o1;
    }
}

extern "C" void kernel_launch(void* const* d_in, const int* in_sizes, int n_in,
                              void* d_out, int out_size, void* d_ws, size_t ws_size,
                              hipStream_t stream) {
    const float* memory   = (const float*)d_in[0];
    const float* query    = (const float*)d_in[1];
    const int*   seq_mask = (const int*)d_in[2];
    float*       out      = (float*)d_out;
    char*        ws       = (char*)d_ws;

    prep_kqm<<<dim3(32), 256, 0, stream>>>(memory, query, seq_mask, ws);
    prep_v<<<dim3(BATCH * NHEADS * 128), 128, 0, stream>>>(memory, ws);
    dim3 grid(SEQ / 32, NHEADS, BATCH);
    attn_fwd<<<grid, 256, 0, stream>>>(ws, out);
}

// Round 9
// 114.583 us; speedup vs baseline: 1.4889x; 1.1574x over previous
//
#include <hip/hip_runtime.h>
#include <hip/hip_bf16.h>

#define UNITS 128
#define NHEADS 8
#define SEQ 4096
#define BATCH 2
#define QSCALE 0.3606737602f   // d^-0.5 * log2(e): logits in log2 domain
#define MASKNEG -1e30f
#define MINIT   -1e4f

typedef __bf16 bf8v __attribute__((ext_vector_type(8)));
typedef float  f4v  __attribute__((ext_vector_type(4)));
typedef float  f16v __attribute__((ext_vector_type(16)));

union BF2  { __bf16 h[2]; unsigned int u; };
union FRAG { unsigned int u[4]; bf8v v; };
union C16  { f16v v; f4v q[4]; };
union BF8U { __bf16 h[8]; bf8v v; };

// workspace layout (bytes)
#define KP_OFF 0u            // K' [B][H][S][16] bf16   : 2 MB
#define QP_OFF (2u << 20)    // Q' [B][H][S][16] bf16   : 2 MB (pre-scaled)
#define VP_OFF (4u << 20)    // V' [B][H][S/32][32][32] : 4 MB (key order sigma-permuted, rows 16-31 = 1.0)
#define MC_OFF (8u << 20)    // maskC [B][128][2][16] f32 : 32 KB (C-operand order)

__device__ __forceinline__ float fmax3(float a, float b, float c) {
    return fmaxf(fmaxf(a, b), c);
}

// sigma: swap bits 2<->3 of the 5-bit within-block key index (involution).
// V' stores key sigma(slot) at slot; then the QK C-layout registers feed the
// PV B-fragment directly (pf = {pk[2ck], pk[2ck+1]}), no cross-lane exchange.
__device__ __forceinline__ int sigma32(int s) {
    return (s & ~12) | ((s & 4) << 1) | ((s & 8) >> 1);
}

// ---------------- prep 1: K', Q' (bf16, head-separated), maskC (C-order) ----
__global__ void prep_kqm(const float* __restrict__ mem, const float* __restrict__ qry,
                         const int* __restrict__ msk, char* __restrict__ ws)
{
    const int gid = blockIdx.x * 256 + threadIdx.x;   // 8192 = B*S
    const int b = gid >> 12, key = gid & 4095;

    // mask -> C-operand permuted order: C row = (r&3) + 8*(r>>2) + 4*hl
    const float mv = msk[b * SEQ + key] ? 0.f : MASKNEG;
    const int pos = key & 31, blkg = key >> 5;
    const int hl = (pos >> 2) & 1;
    const int r  = (pos & 3) | ((pos >> 3) << 2);
    ((float*)(ws + MC_OFF))[((b * 128 + blkg) * 2 + hl) * 16 + r] = mv;

    const float* krow = mem + ((size_t)(b * SEQ + key)) * (2 * UNITS);
    const float* qrow = qry + ((size_t)(b * SEQ + key)) * UNITS;
    #pragma unroll
    for (int h = 0; h < NHEADS; ++h) {
        BF8U lo, hi;
        #pragma unroll
        for (int j = 0; j < 8; ++j) {
            lo.h[j] = (__bf16)krow[h * 16 + j];
            hi.h[j] = (__bf16)krow[h * 16 + 8 + j];
        }
        __bf16* kd = (__bf16*)(ws + KP_OFF) + ((size_t)(b * 8 + h) * SEQ + key) * 16;
        *(bf8v*)kd = lo.v;
        *(bf8v*)(kd + 8) = hi.v;
        #pragma unroll
        for (int j = 0; j < 8; ++j) {
            lo.h[j] = (__bf16)(qrow[h * 16 + j] * QSCALE);
            hi.h[j] = (__bf16)(qrow[h * 16 + 8 + j] * QSCALE);
        }
        __bf16* qd = (__bf16*)(ws + QP_OFF) + ((size_t)(b * 8 + h) * SEQ + key) * 16;
        *(bf8v*)qd = lo.v;
        *(bf8v*)(qd + 8) = hi.v;
    }
}

// ---------------- prep 2: V' transposed + key-permuted, ones rows baked ----
__global__ void prep_v(const float* __restrict__ mem, char* __restrict__ ws)
{
    const int wg = blockIdx.x;                 // B*H*128
    const int b = wg >> 10, rem = wg & 1023;
    const int h = rem >> 7, blk = rem & 127;
    const int t = threadIdx.x;                 // 128

    __shared__ float vt[32][17];
    {
        const int key = t >> 2, q4 = t & 3;
        const float* src = mem + ((size_t)(b * SEQ + blk * 32 + key)) * (2 * UNITS)
                           + UNITS + h * 16 + q4 * 4;
        const f4v v = *(const f4v*)src;
        vt[key][q4 * 4 + 0] = v[0]; vt[key][q4 * 4 + 1] = v[1];
        vt[key][q4 * 4 + 2] = v[2]; vt[key][q4 * 4 + 3] = v[3];
    }
    __syncthreads();
    const int row = t >> 2, c = t & 3;         // row = d-slot 0..31, c = slot-octet
    BF8U o;
    #pragma unroll
    for (int k = 0; k < 8; ++k)
        o.h[k] = (row < 16) ? (__bf16)vt[sigma32(c * 8 + k)][row] : (__bf16)1.0f;
    __bf16* dst = (__bf16*)(ws + VP_OFF)
                  + (((size_t)(b * 8 + h) * 128 + blk) * 32 + row) * 32 + c * 8;
    *(bf8v*)dst = o.v;
}

// ---------------- attention: zero-LDS, zero-exchange main loop ----
__global__ __launch_bounds__(256, 4) void attn_fwd(
    const char* __restrict__ ws, float* __restrict__ out)
{
    const int qblk = blockIdx.x, h = blockIdx.y, b = blockIdx.z;
    const int tid  = threadIdx.x;
    const int wave = tid >> 6;                 // kv quarter
    const int lane = tid & 63, col = lane & 31, hl = lane >> 5;

    __shared__ float mrg[3][32][20];

    const size_t bh = (size_t)(b * 8 + h);
    const char* Kb = ws + KP_OFF + bh * SEQ * 32;
    const char* Qb = ws + QP_OFF + bh * SEQ * 32;
    const char* Vb = ws + VP_OFF + bh * 128 * 2048;
    const char* Mb = ws + MC_OFF + (size_t)b * 128 * 128;

    // Q fragment: B[k=d=hl*8+j][col=q]
    const int qrow = qblk * 32 + col;
    const bf8v qfrag = *(const bf8v*)(Qb + (size_t)qrow * 32 + hl * 16);

    const char* kaddr = Kb + (size_t)(wave * 1024 + col) * 32 + hl * 16;
    const char* vaddr = Vb + (size_t)(wave * 32) * 2048 + col * 64 + hl * 16;
    const char* maddr = Mb + (size_t)(wave * 32) * 128 + hl * 64;

    // prologue: iter-0 fragments
    bf8v kf = *(const bf8v*)kaddr;
    bf8v v0 = *(const bf8v*)vaddr;
    bf8v v1 = *(const bf8v*)(vaddr + 32);

    float m = MINIT;
    f16v acc;
    #pragma unroll
    for (int i = 0; i < 16; ++i) acc[i] = 0.f;

    for (int blk = 0; blk < 32; ++blk) {
        // mask C operand (pre-permuted, L1-hot broadcast)
        C16 cma;
        #pragma unroll
        for (int i = 0; i < 4; ++i) cma.q[i] = *(const f4v*)(maddr + i * 16);

        // QK^T (swapped): D[key][q] = K.Q + maskC
        const f16v sv = __builtin_amdgcn_mfma_f32_32x32x16_bf16(kf, qfrag, cma.v, 0, 0, 0);

        // prefetch next iteration's fragments
        bf8v v0n = v0, v1n = v1;
        if (blk + 1 < 32) {
            kaddr += 1024; vaddr += 2048; maddr += 128;
            kf  = *(const bf8v*)kaddr;
            v0n = *(const bf8v*)vaddr;
            v1n = *(const bf8v*)(vaddr + 32);
        }

        // block max: max3 tree + 1 shfl
        float p0 = fmax3(sv[0], sv[1], sv[2]);
        float p1 = fmax3(sv[3], sv[4], sv[5]);
        float p2 = fmax3(sv[6], sv[7], sv[8]);
        float p3 = fmax3(sv[9], sv[10], sv[11]);
        float p4 = fmax3(sv[12], sv[13], sv[14]);
        float bmax = fmaxf(fmax3(p0, p1, p2), fmax3(p3, p4, sv[15]));
        bmax = fmaxf(bmax, __shfl_xor(bmax, 32));

        // T13 defer-max (log2 domain); acc[8] = running denominator (all lanes)
        if (!__all(bmax <= m + 11.0f)) {
            const float m_new = fmaxf(m, bmax);
            const float sc = exp2f(m - m_new);
            #pragma unroll
            for (int r2 = 0; r2 < 9; ++r2) acc[r2] *= sc;
            m = m_new;
        }

        // exp2 + pack: pk[R][p] = keys {8R+4hl+2p, +1} for q=col
        unsigned int pk[4][2];
        #pragma unroll
        for (int R = 0; R < 4; ++R) {
            #pragma unroll
            for (int p = 0; p < 2; ++p) {
                BF2 a;
                a.h[0] = (__bf16)exp2f(sv[4 * R + 2 * p]     - m);
                a.h[1] = (__bf16)exp2f(sv[4 * R + 2 * p + 1] - m);
                pk[R][p] = a.u;
            }
        }

        // PV: sigma-permuted V' -> B-frag comes straight from registers
        #pragma unroll
        for (int ck = 0; ck < 2; ++ck) {
            FRAG pf;
            pf.u[0] = pk[2 * ck][0];
            pf.u[1] = pk[2 * ck][1];
            pf.u[2] = pk[2 * ck + 1][0];
            pf.u[3] = pk[2 * ck + 1][1];
            acc = __builtin_amdgcn_mfma_f32_32x32x16_bf16(ck ? v1 : v0, pf.v, acc, 0, 0, 0);
        }
        v0 = v0n; v1 = v1n;
    }

    // denominator: V' rows 16-31 = 1.0 -> acc[8] holds sum(P) in every lane
    const float l = acc[8];

    // merge the 4 kv quarters (verified epilogue)
    __syncthreads();
    if (wave != 0) {
        float* row = &mrg[wave - 1][col][0];
        f4v a0, a1;
        #pragma unroll
        for (int i = 0; i < 4; ++i) { a0[i] = acc[i]; a1[i] = acc[4 + i]; }
        *(f4v*)(row + 4 * hl)     = a0;
        *(f4v*)(row + 8 + 4 * hl) = a1;
        if (hl == 0) { row[16] = m; row[17] = l; }
    }
    __syncthreads();
    if (wave == 0) {
        float mw[3], lw[3];
        f4v a0w[3], a1w[3];
        #pragma unroll
        for (int w = 0; w < 3; ++w) {
            const float* row = &mrg[w][col][0];
            a0w[w] = *(const f4v*)(row + 4 * hl);
            a1w[w] = *(const f4v*)(row + 8 + 4 * hl);
            mw[w] = row[16];
            lw[w] = row[17];
        }
        const float M = fmaxf(fmaxf(m, mw[0]), fmaxf(mw[1], mw[2]));
        const float w0 = exp2f(m - M);
        float ww[3];
        #pragma unroll
        for (int w = 0; w < 3; ++w) ww[w] = exp2f(mw[w] - M);
        const float inv = 1.0f / (l * w0 + lw[0] * ww[0] + lw[1] * ww[1] + lw[2] * ww[2]);
        f4v o0, o1;
        #pragma unroll
        for (int i = 0; i < 4; ++i) {
            o0[i] = (acc[i]     * w0 + a0w[0][i] * ww[0] + a0w[1][i] * ww[1] + a0w[2][i] * ww[2]) * inv;
            o1[i] = (acc[4 + i] * w0 + a1w[0][i] * ww[0] + a1w[1][i] * ww[1] + a1w[2][i] * ww[2]) * inv;
        }
        float* op = out + ((size_t)b * SEQ + qrow) * UNITS + h * 16;
        *(f4v*)(op + 4 * hl)     = o0;
        *(f4v*)(op + 8 + 4 * hl) = o1;
    }
}

extern "C" void kernel_launch(void* const* d_in, const int* in_sizes, int n_in,
                              void* d_out, int out_size, void* d_ws, size_t ws_size,
                              hipStream_t stream) {
    const float* memory   = (const float*)d_in[0];
    const float* query    = (const float*)d_in[1];
    const int*   seq_mask = (const int*)d_in[2];
    float*       out      = (float*)d_out;
    char*        ws       = (char*)d_ws;

    prep_kqm<<<dim3(32), 256, 0, stream>>>(memory, query, seq_mask, ws);
    prep_v<<<dim3(BATCH * NHEADS * 128), 128, 0, stream>>>(memory, ws);
    dim3 grid(SEQ / 32, NHEADS, BATCH);
    attn_fwd<<<grid, 256, 0, stream>>>(ws, out);
}